// Round 2
// baseline (236.607 us; speedup 1.0000x reference)
//
#include <hip/hip_runtime.h>
#include <math.h>

// Problem constants (B=4, S=2048, D=2048, E=64, K=2)
#define NTOK   8192      // B*S
#define DDIM   2048
#define NEXP   64
#define TOPK   2
#define TPB    16        // tokens per block
#define NWAVE  4         // waves per block, split K
#define KSLICE (DDIM / NWAVE)   // 512
#define NGRP   (KSLICE / 4)     // 128 k-groups of 4 per wave

#define GATED_SZ (NTOK * NEXP)          // 524288
#define IDX_OFF  GATED_SZ               // 524288
#define VALS_OFF (GATED_SZ + NTOK * 2)  // 540672

// ---------------------------------------------------------------------------
// Pack W [E=64][D=2048] (row-major) into Wp [g=512][e=64][4] so that the main
// kernel's per-lane (lane=expert) float4 load of k-group g is fully coalesced:
// Wp[(g*64+e)] = W4[e*512 + g].  0.5 MB, one tiny kernel.
// ---------------------------------------------------------------------------
__global__ void pack_w_kernel(const float4* __restrict__ W4,
                              float4* __restrict__ Wp)
{
    const int tid = blockIdx.x * blockDim.x + threadIdx.x;  // 0..32767
    const int e = tid & 63;
    const int g = tid >> 6;
    Wp[tid] = W4[e * (DDIM / 4) + g];   // writes coalesced; reads strided (tiny)
}

// ---------------------------------------------------------------------------
// Main fused kernel: logits GEMM (fp32 VALU) + noise + top-2 + softmax + scatter
// Block: 256 threads = 4 waves; each wave: 16 tokens x K-slice of 512.
// lane = expert; x loads are wave-uniform (broadcast); W loads coalesced (Wp).
// ---------------------------------------------------------------------------
__global__ __launch_bounds__(256, 2) void moe_gate_kernel(
    const float* __restrict__ x,
    const float4* __restrict__ Wp,
    const float* __restrict__ noise_w,
    const float* __restrict__ noise,
    float* __restrict__ out)
{
    // partial dot products: [token][wave][expert] = 16 KB
    __shared__ float part[TPB * NWAVE * NEXP];

    const int lane = threadIdx.x & 63;
    const int wv   = __builtin_amdgcn_readfirstlane((int)(threadIdx.x >> 6));
    const int e    = lane;                 // lane == expert
    const int tokBase = blockIdx.x * TPB;
    const int kOff = wv * KSLICE;

    float acc[TPB];
#pragma unroll
    for (int t = 0; t < TPB; ++t) acc[t] = 0.f;

    // coalesced W^T: group g (global) lives at Wp[g*64 + e]
    const float4* wp = Wp + (size_t)(kOff >> 2) * NEXP + e;
    const float*  xb = x + (size_t)tokBase * DDIM + kOff;

#pragma unroll 2
    for (int q = 0; q < NGRP; ++q) {
        const float4 wq = wp[(size_t)q * NEXP];
#pragma unroll
        for (int t = 0; t < TPB; ++t) {
            // wave-uniform address -> broadcast load
            const float4 xq = *(const float4*)(xb + (size_t)t * DDIM + q * 4);
            acc[t] = fmaf(wq.x, xq.x, acc[t]);
            acc[t] = fmaf(wq.y, xq.y, acc[t]);
            acc[t] = fmaf(wq.z, xq.z, acc[t]);
            acc[t] = fmaf(wq.w, xq.w, acc[t]);
        }
    }

#pragma unroll
    for (int t = 0; t < TPB; ++t)
        part[(t * NWAVE + wv) * NEXP + e] = acc[t];
    __syncthreads();

    // Epilogue: wave wv handles tokens wv*4 .. wv*4+3
#pragma unroll
    for (int i = 0; i < 4; ++i) {
        const int t   = wv * 4 + i;
        const int tok = tokBase + t;

        float v = part[(t * NWAVE + 0) * NEXP + e]
                + part[(t * NWAVE + 1) * NEXP + e]
                + part[(t * NWAVE + 2) * NEXP + e]
                + part[(t * NWAVE + 3) * NEXP + e];

        // noise injection (fp32, matches reference order)
        v += noise[(size_t)tok * NEXP + e] * noise_w[e];

        // top-1: butterfly max with lax.top_k tie-break (lower index wins)
        float m1 = v; int i1 = e;
#pragma unroll
        for (int s = 32; s > 0; s >>= 1) {
            float ov = __shfl_xor(m1, s, 64);
            int   oi = __shfl_xor(i1, s, 64);
            if (ov > m1 || (ov == m1 && oi < i1)) { m1 = ov; i1 = oi; }
        }
        // top-2: mask winner, reduce again
        float vm = (e == i1) ? -INFINITY : v;
        float m2 = vm; int i2 = e;
#pragma unroll
        for (int s = 32; s > 0; s >>= 1) {
            float ov = __shfl_xor(m2, s, 64);
            int   oi = __shfl_xor(i2, s, 64);
            if (ov > m2 || (ov == m2 && oi < i2)) { m2 = ov; i2 = oi; }
        }

        // softmax over (m1, m2); m1 >= m2 so max = m1
        const float e2 = expf(m2 - m1);
        const float inv = 1.f / (1.f + e2);
        const float p1 = inv;
        const float p2 = e2 * inv;

        // gated: zeros everywhere except top-2 slots (d_out is poisoned -> write zeros)
        float g = 0.f;
        if (e == i1) g = p1;
        else if (e == i2) g = p2;
        out[(size_t)tok * NEXP + e] = g;

        if (lane == 0) {
            out[IDX_OFF  + tok * 2 + 0] = (float)i1;
            out[IDX_OFF  + tok * 2 + 1] = (float)i2;
            out[VALS_OFF + tok * 2 + 0] = m1;
            out[VALS_OFF + tok * 2 + 1] = m2;
        }
    }
}

extern "C" void kernel_launch(void* const* d_in, const int* in_sizes, int n_in,
                              void* d_out, int out_size, void* d_ws, size_t ws_size,
                              hipStream_t stream) {
    const float* x      = (const float*)d_in[0];
    const float* W      = (const float*)d_in[1];
    const float* nw     = (const float*)d_in[2];
    const float* noise  = (const float*)d_in[3];
    // d_in[4] is k==2, hardcoded
    float* out = (float*)d_out;
    float4* Wp = (float4*)d_ws;   // 512 KB scratch: packed W^T

    // pack W: 32768 float4 moves
    hipLaunchKernelGGL(pack_w_kernel, dim3(128), dim3(256), 0, stream,
                       (const float4*)W, Wp);

    hipLaunchKernelGGL(moe_gate_kernel, dim3(NTOK / TPB), dim3(256), 0, stream,
                       x, (const float4*)Wp, nw, noise, out);
}

// Round 3
// 155.102 us; speedup vs baseline: 1.5255x; 1.5255x over previous
//
#include <hip/hip_runtime.h>
#include <math.h>

// Problem constants (B=4, S=2048, D=2048, E=64, K=2)
#define NTOK   8192      // B*S
#define DDIM   2048
#define NEXP   64
#define TPB    16        // tokens per block
#define NWAVE  8         // waves per block (512 threads)
#define BK     128       // K-chunk (floats) staged per iteration
#define NCHUNK (DDIM / BK)   // 16
#define GPC    (BK / 4)      // 32 float4 groups per chunk
#define GPW    (GPC / NWAVE) // 4 groups per wave per chunk

#define GATED_SZ (NTOK * NEXP)          // 524288
#define IDX_OFF  GATED_SZ               // 524288
#define VALS_OFF (GATED_SZ + NTOK * 2)  // 540672

// ---------------------------------------------------------------------------
// Pack W [E=64][D=2048] row-major into Wp [g=512][e=64] float4 so the main
// kernel's per-lane (lane=expert) float4 load of k-group g is fully coalesced.
// ---------------------------------------------------------------------------
__global__ void pack_w_kernel(const float4* __restrict__ W4,
                              float4* __restrict__ Wp)
{
    const int tid = blockIdx.x * blockDim.x + threadIdx.x;  // 0..32767
    const int e = tid & 63;
    const int g = tid >> 6;
    Wp[tid] = W4[e * (DDIM / 4) + g];
}

// ---------------------------------------------------------------------------
// Fused gate kernel. Block: 512 threads = 8 waves, 16 tokens.
// K-loop: stage x-chunk [16 tok x 128 k] into LDS via per-lane coalesced
// vector loads (register double-buffered); waves split the chunk 8-ways;
// x read back via uniform-address broadcast ds_read_b128; W via packed Wp.
// lane = expert throughout; epilogue = noise + top-2 + softmax + scatter.
// ---------------------------------------------------------------------------
__global__ __launch_bounds__(512, 4) void moe_gate_kernel(
    const float* __restrict__ x,
    const float4* __restrict__ Wp,
    const float* __restrict__ noise_w,
    const float* __restrict__ noise,
    float* __restrict__ out)
{
    __shared__ float4 xbuf[2][TPB * GPC];     // 2 x 8 KB
    __shared__ float  part[TPB * NWAVE * NEXP]; // 32 KB

    const int tid  = threadIdx.x;
    const int lane = tid & 63;
    const int wv   = __builtin_amdgcn_readfirstlane(tid >> 6);
    const int e    = lane;                    // lane == expert
    const int tokBase = blockIdx.x * TPB;

    // staging coords: thread loads x[tokBase+srow][chunk*128 + scol*4 ..+3]
    const int srow = tid >> 5;                // 0..15 (token row)
    const int scol = tid & 31;                // 0..31 (float4 col in chunk)
    const float4* xsrc = (const float4*)(x + (size_t)(tokBase + srow) * DDIM) + scol;
    const int sidx = srow * GPC + scol;

    const float4* wp = Wp + e;                // + group*64 per load

    float acc[TPB];
#pragma unroll
    for (int t = 0; t < TPB; ++t) acc[t] = 0.f;

    float4 stage = xsrc[0];
    int buf = 0;
    for (int c = 0; c < NCHUNK; ++c) {
        xbuf[buf][sidx] = stage;
        if (c + 1 < NCHUNK) stage = xsrc[(size_t)(c + 1) * GPC];
        __syncthreads();

        const int gbase = c * GPC + wv * GPW;
#pragma unroll
        for (int j = 0; j < GPW; ++j) {
            const float4 wq = wp[(size_t)(gbase + j) * NEXP];
            const float4* xr = &xbuf[buf][wv * GPW + j];
#pragma unroll
            for (int t = 0; t < TPB; ++t) {
                const float4 xq = xr[t * GPC];   // uniform addr -> LDS broadcast
                acc[t] = fmaf(wq.x, xq.x, acc[t]);
                acc[t] = fmaf(wq.y, xq.y, acc[t]);
                acc[t] = fmaf(wq.z, xq.z, acc[t]);
                acc[t] = fmaf(wq.w, xq.w, acc[t]);
            }
        }
        buf ^= 1;
        // NOTE: single barrier per iter is safe with the double buffer:
        // iter c+2's write to this buffer can only start after sync(c+1),
        // which requires compute(c) (the last reader) to have finished.
    }

#pragma unroll
    for (int t = 0; t < TPB; ++t)
        part[(t * NWAVE + wv) * NEXP + e] = acc[t];
    __syncthreads();

    // Epilogue: wave wv handles tokens wv*2, wv*2+1
#pragma unroll
    for (int i = 0; i < 2; ++i) {
        const int t   = wv * 2 + i;
        const int tok = tokBase + t;

        float v = 0.f;
#pragma unroll
        for (int w = 0; w < NWAVE; ++w)
            v += part[(t * NWAVE + w) * NEXP + e];

        // noise injection (fp32, matches reference order)
        v += noise[(size_t)tok * NEXP + e] * noise_w[e];

        // top-1: butterfly max with lax.top_k tie-break (lower index wins)
        float m1 = v; int i1 = e;
#pragma unroll
        for (int s = 32; s > 0; s >>= 1) {
            float ov = __shfl_xor(m1, s, 64);
            int   oi = __shfl_xor(i1, s, 64);
            if (ov > m1 || (ov == m1 && oi < i1)) { m1 = ov; i1 = oi; }
        }
        // top-2: mask winner, reduce again
        float vm = (e == i1) ? -INFINITY : v;
        float m2 = vm; int i2 = e;
#pragma unroll
        for (int s = 32; s > 0; s >>= 1) {
            float ov = __shfl_xor(m2, s, 64);
            int   oi = __shfl_xor(i2, s, 64);
            if (ov > m2 || (ov == m2 && oi < i2)) { m2 = ov; i2 = oi; }
        }

        // softmax over (m1, m2); m1 >= m2 so max = m1
        const float e2 = expf(m2 - m1);
        const float inv = 1.f / (1.f + e2);
        const float p1 = inv;
        const float p2 = e2 * inv;

        // gated: zeros everywhere except top-2 slots (d_out is poisoned)
        float g = 0.f;
        if (e == i1) g = p1;
        else if (e == i2) g = p2;
        out[(size_t)tok * NEXP + e] = g;

        if (lane == 0) {
            out[IDX_OFF  + tok * 2 + 0] = (float)i1;
            out[IDX_OFF  + tok * 2 + 1] = (float)i2;
            out[VALS_OFF + tok * 2 + 0] = m1;
            out[VALS_OFF + tok * 2 + 1] = m2;
        }
    }
}

extern "C" void kernel_launch(void* const* d_in, const int* in_sizes, int n_in,
                              void* d_out, int out_size, void* d_ws, size_t ws_size,
                              hipStream_t stream) {
    const float* x      = (const float*)d_in[0];
    const float* W      = (const float*)d_in[1];
    const float* nw     = (const float*)d_in[2];
    const float* noise  = (const float*)d_in[3];
    // d_in[4] is k==2, hardcoded
    float* out = (float*)d_out;
    float4* Wp = (float4*)d_ws;   // 512 KB scratch: packed W^T

    hipLaunchKernelGGL(pack_w_kernel, dim3(128), dim3(256), 0, stream,
                       (const float4*)W, Wp);

    hipLaunchKernelGGL(moe_gate_kernel, dim3(NTOK / TPB), dim3(512), 0, stream,
                       x, (const float4*)Wp, nw, noise, out);
}

// Round 4
// 149.789 us; speedup vs baseline: 1.5796x; 1.0355x over previous
//
#include <hip/hip_runtime.h>
#include <math.h>

// Problem constants (B=4, S=2048, D=2048, E=64, K=2)
#define NTOK   8192
#define DDIM   2048
#define NEXP   64
#define NGRP_T 128          // token-groups of 64
#define KHALF  1024         // K split 2-ways across blocks
#define NWAVE  8            // waves per main block (512 thr)
#define BK     128          // k-chunk staged per iteration
#define NCHUNK (KHALF / BK) // 8
#define KSUB   (BK / NWAVE) // 16 k per wave per chunk
#define XPAD   65           // padded t-stride breaks staging-write conflicts

#define GATED_SZ (NTOK * NEXP)          // 524288
#define IDX_OFF  GATED_SZ
#define VALS_OFF (GATED_SZ + NTOK * 2)

// ws layout (floats): Wt [0 .. 131072) then Lp [131072 .. 131072 + 1048576)
#define WT_FLOATS (NEXP * DDIM)         // 131072 (512 KB)
#define LP_HALF   (NGRP_T * NEXP * 64)  // 524288 floats per K-half (2 MB)

// ---------------------------------------------------------------------------
// Pack W [E][D] row-major -> Wt [k][e] so the main kernel's wave-uniform read
// of one k-row (64 floats, 256 B) is a dense s_load target.
// ---------------------------------------------------------------------------
__global__ void pack_w_kernel(const float* __restrict__ W,
                              float* __restrict__ Wt)
{
    const int tid = blockIdx.x * blockDim.x + threadIdx.x;  // 0..131071
    const int e = tid & 63;
    const int k = tid >> 6;
    Wt[tid] = W[e * DDIM + k];   // Wt[k*64+e]; writes coalesced
}

// ---------------------------------------------------------------------------
// Main GEMM kernel: lane = token, experts in registers (acc[64]),
// W wave-uniform from Wt via the scalar path.
// Block (g, s): token-group g (64 tokens) x K-half s. 512 thr = 8 waves.
// Per chunk (128 k): cooperative staging x -> LDS transposed [k][t];
// wave w computes k-sub [w*16, +16): 1 ds_read_b32 feeds 64 FMAs.
// Ends with cross-wave reduction -> partial logits Lp[s][g][e][t].
// ---------------------------------------------------------------------------
__global__ __launch_bounds__(512, 2) void logits_kernel(
    const float* __restrict__ x,
    const float* __restrict__ wt,
    float* __restrict__ lp)
{
    __shared__ float xl[2][BK * XPAD];          // 2 x 33.3 KB
    __shared__ float red[NWAVE * 8 * 64];       // 16 KB

    const int tid  = threadIdx.x;
    const int lane = tid & 63;                  // token within group
    const int w    = __builtin_amdgcn_readfirstlane(tid >> 6);
    const int g    = blockIdx.x & (NGRP_T - 1);
    const int s    = blockIdx.x >> 7;
    const int kbase = s * KHALF;

    // staging: thread covers token t0, 16 consecutive k starting at k0
    const int t0 = tid >> 3;                    // 0..63
    const int k0 = (tid & 7) * 16;              // 0..112
    const float* xsrc = x + (size_t)(g * 64 + t0) * DDIM + kbase + k0;

    float acc[NEXP];
#pragma unroll
    for (int e = 0; e < NEXP; ++e) acc[e] = 0.f;

    float4 stg[4];
#pragma unroll
    for (int q = 0; q < 4; ++q) stg[q] = *(const float4*)(xsrc + 4 * q);

    int buf = 0;
    for (int c = 0; c < NCHUNK; ++c) {
        // stage (transpose): xl[k][t]
#pragma unroll
        for (int q = 0; q < 4; ++q) {
#pragma unroll
            for (int j = 0; j < 4; ++j)
                xl[buf][(k0 + 4 * q + j) * XPAD + t0] = ((const float*)&stg[q])[j];
        }
        if (c + 1 < NCHUNK) {
#pragma unroll
            for (int q = 0; q < 4; ++q)
                stg[q] = *(const float4*)(xsrc + (size_t)(c + 1) * BK + 4 * q);
        }
        __syncthreads();
        // single barrier per iter is safe with the double buffer: a wave can
        // only write buffer b at iter c+2 after all waves passed barrier c+1,
        // which they reach only after computing iter c from buffer b.

        const int kw = w * KSUB;
#pragma unroll 4
        for (int kk = 0; kk < KSUB; ++kk) {
            const float xv = xl[buf][(kw + kk) * XPAD + lane];
            const size_t krow = (size_t)(kbase + c * BK + kw + kk) * NEXP;
#pragma unroll
            for (int e = 0; e < NEXP; ++e)
                acc[e] = fmaf(xv, wt[krow + e], acc[e]);  // wt: uniform -> s_load
        }
        buf ^= 1;
    }

    // cross-wave reduction: 8 passes of 8 experts
    for (int p = 0; p < 8; ++p) {
#pragma unroll
        for (int j = 0; j < 8; ++j)
            red[(w * 8 + j) * 64 + lane] = acc[p * 8 + j];
        __syncthreads();
        {
            const int j2 = tid >> 6;        // expert sub-index 0..7
            const int t2 = tid & 63;        // token
            float sum = 0.f;
#pragma unroll
            for (int w2 = 0; w2 < NWAVE; ++w2)
                sum += red[(w2 * 8 + j2) * 64 + t2];
            lp[(size_t)s * LP_HALF + ((size_t)g * 64 + p * 8 + j2) * 64 + t2] = sum;
        }
        __syncthreads();
    }
}

// ---------------------------------------------------------------------------
// Epilogue: sum the two K-half partials, add noise, top-2 + softmax + scatter.
// Grid 2048 blocks x 256 thr; each wave owns one token; lane = expert.
// ---------------------------------------------------------------------------
__global__ __launch_bounds__(256, 4) void gate_kernel(
    const float* __restrict__ lp,
    const float* __restrict__ noise_w,
    const float* __restrict__ noise,
    float* __restrict__ out)
{
    const int lane = threadIdx.x & 63;
    const int wv   = threadIdx.x >> 6;
    const int e    = lane;
    const int tok  = blockIdx.x * 4 + wv;       // 0..8191
    const int g    = tok >> 6;
    const int t    = tok & 63;

    const size_t pe = ((size_t)g * 64 + e) * 64 + t;   // Lp[g][e][t]
    float v = lp[pe] + lp[LP_HALF + pe]
            + noise[(size_t)tok * NEXP + e] * noise_w[e];

    // top-1: butterfly max with lax.top_k tie-break (lower index wins)
    float m1 = v; int i1 = e;
#pragma unroll
    for (int s = 32; s > 0; s >>= 1) {
        float ov = __shfl_xor(m1, s, 64);
        int   oi = __shfl_xor(i1, s, 64);
        if (ov > m1 || (ov == m1 && oi < i1)) { m1 = ov; i1 = oi; }
    }
    // top-2: mask winner, reduce again
    float vm = (e == i1) ? -INFINITY : v;
    float m2 = vm; int i2 = e;
#pragma unroll
    for (int s = 32; s > 0; s >>= 1) {
        float ov = __shfl_xor(m2, s, 64);
        int   oi = __shfl_xor(i2, s, 64);
        if (ov > m2 || (ov == m2 && oi < i2)) { m2 = ov; i2 = oi; }
    }

    // softmax over (m1, m2); m1 >= m2
    const float e2  = expf(m2 - m1);
    const float inv = 1.f / (1.f + e2);
    const float p1  = inv;
    const float p2  = e2 * inv;

    // gated: zeros everywhere except top-2 slots (d_out is poisoned)
    float gval = 0.f;
    if (e == i1) gval = p1;
    else if (e == i2) gval = p2;
    out[(size_t)tok * NEXP + e] = gval;

    if (lane == 0) {
        out[IDX_OFF  + tok * 2 + 0] = (float)i1;
        out[IDX_OFF  + tok * 2 + 1] = (float)i2;
        out[VALS_OFF + tok * 2 + 0] = m1;
        out[VALS_OFF + tok * 2 + 1] = m2;
    }
}

extern "C" void kernel_launch(void* const* d_in, const int* in_sizes, int n_in,
                              void* d_out, int out_size, void* d_ws, size_t ws_size,
                              hipStream_t stream) {
    const float* x      = (const float*)d_in[0];
    const float* W      = (const float*)d_in[1];
    const float* nw     = (const float*)d_in[2];
    const float* noise  = (const float*)d_in[3];
    // d_in[4] is k==2, hardcoded
    float* out = (float*)d_out;

    float* Wt = (float*)d_ws;                 // 512 KB
    float* Lp = (float*)d_ws + WT_FLOATS;     // 4 MB partial logits

    hipLaunchKernelGGL(pack_w_kernel, dim3(WT_FLOATS / 256), dim3(256), 0, stream,
                       W, Wt);

    hipLaunchKernelGGL(logits_kernel, dim3(NGRP_T * 2), dim3(512), 0, stream,
                       x, Wt, Lp);

    hipLaunchKernelGGL(gate_kernel, dim3(NTOK / 4), dim3(256), 0, stream,
                       Lp, nw, noise, out);
}

// Round 5
// 146.194 us; speedup vs baseline: 1.6184x; 1.0246x over previous
//
#include <hip/hip_runtime.h>
#include <math.h>

// Problem constants (B=4, S=2048, D=2048, E=64, K=2)
#define NTOK   8192
#define DDIM   2048
#define NEXP   64
#define TGRP   32               // tokens per block
#define NGRP   (NTOK / TGRP)    // 256 token groups
#define KSPL   2                // K split across blocks
#define KSLICE (DDIM / KSPL)    // 1024 k per block
#define NWAVE  8                // waves per block (512 thr)
#define BK     64               // k staged per chunk
#define NCHUNK (KSLICE / BK)    // 16
#define KSUB   (BK / NWAVE)     // 8 k per wave per chunk
#define XSTR   68               // xl row stride (floats): pad keeps reads conflict-free

#define GATED_SZ (NTOK * NEXP)
#define IDX_OFF  GATED_SZ
#define VALS_OFF (GATED_SZ + NTOK * 2)

#define WT_FLOATS (NEXP * DDIM)        // 131072 floats (512 KB)
#define LPH       (NGRP * NEXP * TGRP) // 524288 floats per K-split (2 MB)

// ---------------------------------------------------------------------------
// Pack W [E][D] -> Wt [k][e] so W k-rows are 256 B contiguous vectors.
// ---------------------------------------------------------------------------
__global__ void pack_w_kernel(const float* __restrict__ W,
                              float* __restrict__ Wt)
{
    const int tid = blockIdx.x * blockDim.x + threadIdx.x;  // 0..131071
    const int e = tid & 63;
    const int k = tid >> 6;
    Wt[tid] = W[e * DDIM + k];
}

// ---------------------------------------------------------------------------
// Logits GEMM. Block: 512 thr = 8 waves; 32 tokens x 1024 k (K-half).
// Lane tile: t8 = lane>>3 (token sub), e8 = lane&7 (expert sub);
// thread owns acc[4 tokens (t8+8i)][8 experts (e8*8+j)].
// Per k: 4 ds_read_b32 x-broadcast (conflict-free, stride 68) +
//        2 global_load_dwordx4 of W (per-lane, vmcnt path) + 32 FMAs.
// No inner-loop scalar data loads -> lgkm stream is pure LDS.
// ---------------------------------------------------------------------------
__global__ __launch_bounds__(512, 4) void logits_kernel(
    const float* __restrict__ x,
    const float* __restrict__ wt,
    float* __restrict__ lp)
{
    __shared__ float xl[TGRP * XSTR];         // 8.7 KB
    __shared__ float red[NWAVE * TGRP * 8];   // 8 KB

    const int tid  = threadIdx.x;
    const int lane = tid & 63;
    const int w    = __builtin_amdgcn_readfirstlane(tid >> 6);
    const int t8   = lane >> 3;               // 0..7
    const int e8   = lane & 7;                // 0..7
    const int g    = blockIdx.x & (NGRP - 1);
    const int s    = blockIdx.x >> 8;         // K-half index
    const int kbase = s * KSLICE;

    // staging: thread loads one float4 of x per chunk (coalesced 256 B/row)
    const int srow = tid >> 4;                // 0..31
    const int scol = tid & 15;                // 0..15
    const float* xsrc = x + (size_t)(g * TGRP + srow) * DDIM + kbase + scol * 4;

    // per-lane W base: expert slice e8*8, k-rows of 64 floats
    const float* wbase = wt + (size_t)kbase * NEXP + e8 * 8;

    float acc[4][8];
#pragma unroll
    for (int i = 0; i < 4; ++i)
#pragma unroll
        for (int j = 0; j < 8; ++j) acc[i][j] = 0.f;

    float4 stage = *(const float4*)xsrc;

    for (int c = 0; c < NCHUNK; ++c) {
        __syncthreads();   // all waves done reading xl for chunk c-1
        *(float4*)(&xl[srow * XSTR + scol * 4]) = stage;
        if (c + 1 < NCHUNK)
            stage = *(const float4*)(xsrc + (size_t)(c + 1) * BK);
        __syncthreads();   // xl ready

        const int klw = w * KSUB;             // wave's k offset in chunk
#pragma unroll
        for (int kk = 0; kk < KSUB; ++kk) {
            const int kl = klw + kk;
            const float* wrow = wbase + (size_t)(c * BK + kl) * NEXP;
            const float4 w0 = *(const float4*)(wrow);       // experts e8*8..+3
            const float4 w1 = *(const float4*)(wrow + 4);   // experts e8*8+4..+7
            float xv[4];
#pragma unroll
            for (int i = 0; i < 4; ++i)
                xv[i] = xl[(t8 + 8 * i) * XSTR + kl];       // 8-fold broadcast
#pragma unroll
            for (int i = 0; i < 4; ++i) {
                acc[i][0] = fmaf(xv[i], w0.x, acc[i][0]);
                acc[i][1] = fmaf(xv[i], w0.y, acc[i][1]);
                acc[i][2] = fmaf(xv[i], w0.z, acc[i][2]);
                acc[i][3] = fmaf(xv[i], w0.w, acc[i][3]);
                acc[i][4] = fmaf(xv[i], w1.x, acc[i][4]);
                acc[i][5] = fmaf(xv[i], w1.y, acc[i][5]);
                acc[i][6] = fmaf(xv[i], w1.z, acc[i][6]);
                acc[i][7] = fmaf(xv[i], w1.w, acc[i][7]);
            }
        }
    }

    // cross-wave reduction: 8 passes over expert-within-slice j
    for (int j = 0; j < 8; ++j) {
        __syncthreads();   // red reuse safe
#pragma unroll
        for (int i = 0; i < 4; ++i)
            red[(w * TGRP + (t8 + 8 * i)) * 8 + e8] = acc[i][j];
        __syncthreads();
        if (tid < TGRP * 8) {                 // 256 outputs this pass
            const int e8o = tid >> 5;         // 0..7
            const int to  = tid & 31;         // token
            float sum = 0.f;
#pragma unroll
            for (int w2 = 0; w2 < NWAVE; ++w2)
                sum += red[w2 * (TGRP * 8) + to * 8 + e8o];
            const int e = e8o * 8 + j;
            lp[(size_t)s * LPH + ((size_t)g * NEXP + e) * TGRP + to] = sum;
        }
    }
}

// ---------------------------------------------------------------------------
// Epilogue: sum K-half partials, add noise, top-2 + softmax + scatter.
// 2048 blocks x 256 thr; wave per token; lane = expert.
// ---------------------------------------------------------------------------
__global__ __launch_bounds__(256, 4) void gate_kernel(
    const float* __restrict__ lp,
    const float* __restrict__ noise_w,
    const float* __restrict__ noise,
    float* __restrict__ out)
{
    const int lane = threadIdx.x & 63;
    const int wv   = threadIdx.x >> 6;
    const int e    = lane;
    const int tok  = blockIdx.x * 4 + wv;
    const int g    = tok >> 5;
    const int t    = tok & 31;

    const size_t pe = ((size_t)g * NEXP + e) * TGRP + t;
    float v = lp[pe] + lp[LPH + pe]
            + noise[(size_t)tok * NEXP + e] * noise_w[e];

    // top-1: butterfly max, lax.top_k tie-break (lower index wins)
    float m1 = v; int i1 = e;
#pragma unroll
    for (int s = 32; s > 0; s >>= 1) {
        float ov = __shfl_xor(m1, s, 64);
        int   oi = __shfl_xor(i1, s, 64);
        if (ov > m1 || (ov == m1 && oi < i1)) { m1 = ov; i1 = oi; }
    }
    float vm = (e == i1) ? -INFINITY : v;
    float m2 = vm; int i2 = e;
#pragma unroll
    for (int s = 32; s > 0; s >>= 1) {
        float ov = __shfl_xor(m2, s, 64);
        int   oi = __shfl_xor(i2, s, 64);
        if (ov > m2 || (ov == m2 && oi < i2)) { m2 = ov; i2 = oi; }
    }

    const float e2  = expf(m2 - m1);
    const float inv = 1.f / (1.f + e2);
    const float p1  = inv;
    const float p2  = e2 * inv;

    float gval = 0.f;
    if (e == i1) gval = p1;
    else if (e == i2) gval = p2;
    out[(size_t)tok * NEXP + e] = gval;

    if (lane == 0) {
        out[IDX_OFF  + tok * 2 + 0] = (float)i1;
        out[IDX_OFF  + tok * 2 + 1] = (float)i2;
        out[VALS_OFF + tok * 2 + 0] = m1;
        out[VALS_OFF + tok * 2 + 1] = m2;
    }
}

extern "C" void kernel_launch(void* const* d_in, const int* in_sizes, int n_in,
                              void* d_out, int out_size, void* d_ws, size_t ws_size,
                              hipStream_t stream) {
    const float* x      = (const float*)d_in[0];
    const float* W      = (const float*)d_in[1];
    const float* nw     = (const float*)d_in[2];
    const float* noise  = (const float*)d_in[3];
    // d_in[4] is k==2, hardcoded
    float* out = (float*)d_out;

    float* Wt = (float*)d_ws;                 // 512 KB
    float* Lp = (float*)d_ws + WT_FLOATS;     // 4 MB partial logits (2 K-halves)

    hipLaunchKernelGGL(pack_w_kernel, dim3(WT_FLOATS / 256), dim3(256), 0, stream,
                       W, Wt);

    hipLaunchKernelGGL(logits_kernel, dim3(NGRP * KSPL), dim3(512), 0, stream,
                       x, Wt, Lp);

    hipLaunchKernelGGL(gate_kernel, dim3(NTOK / 4), dim3(256), 0, stream,
                       Lp, nw, noise, out);
}

// Round 6
// 116.814 us; speedup vs baseline: 2.0255x; 1.2515x over previous
//
#include <hip/hip_runtime.h>
#include <math.h>

// Problem: B=4,S=2048,D=2048,E=64,K=2 -> tokens 8192, K-dim 2048, experts 64
#define NTOK 8192
#define DDIM 2048
#define NEXP 64
#define MT   16          // tokens per block
#define BK   64          // k per chunk
#define KHALF 1024       // per-block K-split half
#define NCH  (KHALF / BK) // 16 chunks
#define XSTR 72          // x LDS row stride (halves) — uniform bank load
#define CSTR 66          // C-buffer row stride (floats)

typedef _Float16 f16x8 __attribute__((ext_vector_type(8)));
typedef _Float16 f16x4 __attribute__((ext_vector_type(4)));
typedef float    f32x4 __attribute__((ext_vector_type(4)));

#define GATED_SZ (NTOK * NEXP)
#define IDX_OFF  GATED_SZ
#define VALS_OFF (GATED_SZ + NTOK * 2)

#define NKSTEP (DDIM / 32)            // 64 MFMA k-steps
#define NTILE  (NEXP / 16)            // 4 n-tiles
#define BFRAG_HALVES ((size_t)NKSTEP * NTILE * 64 * 8)   // 131072 halves = 256 KB

// ---------------------------------------------------------------------------
// Pack W [E=64][D=2048] into MFMA B-fragments (fp16 hi + scaled lo).
// Frag (ks, nt): lane holds B[k=ks*32+(lane>>4)*8+j][n=nt*16+(lane&15)],
// i.e. Wt[k][e] = W[e][k]. lo pre-scaled by 4096 (no fp16 denorms).
// Layout: Bh[((ks*4+nt)*64+lane)*8 + j]  -> per-frag 1KB, lane-contiguous.
// ---------------------------------------------------------------------------
__global__ void pack_b_kernel(const float* __restrict__ W,
                              _Float16* __restrict__ Bh,
                              _Float16* __restrict__ Bl)
{
    const int tid  = blockIdx.x * blockDim.x + threadIdx.x;  // 0..16383
    const int lane = tid & 63;
    const int fid  = tid >> 6;          // 0..255
    const int ks   = fid >> 2;          // k-step
    const int nt   = fid & 3;           // n-tile
    const int e    = nt * 16 + (lane & 15);
    const int k    = ks * 32 + (lane >> 4) * 8;
    const float* src = W + (size_t)e * DDIM + k;   // 8 contiguous fp32

    f16x8 hi, lo;
#pragma unroll
    for (int j = 0; j < 8; ++j) {
        const float v = src[j];
        const _Float16 h = (_Float16)v;
        hi[j] = h;
        lo[j] = (_Float16)((v - (float)h) * 4096.f);
    }
    *(f16x8*)(Bh + (size_t)tid * 8) = hi;   // coalesced 1KB/wave
    *(f16x8*)(Bl + (size_t)tid * 8) = lo;
}

// ---------------------------------------------------------------------------
// Fused gate kernel. 512 blocks x 512 thr; block = 16 tokens, full E=64.
// 8 waves = s (K-half) x nt (16-expert tile). Per 64-k chunk:
//   stage x fp32 -> in-reg split -> xh/xl LDS; 4 ds_read_b128 A-frags;
//   4 coalesced B-frag loads (L1/L2-hot); 6 mfma_f32_16x16x32_f16.
// logits = acc_hh + 2^-12 * acc_lo  (x_lo,w_lo pre-scaled by 4096).
// Epilogue in-block: sum K-halves via LDS C-buf, noise, top-2, softmax.
// ---------------------------------------------------------------------------
__global__ __launch_bounds__(512, 4) void gate_kernel(
    const float* __restrict__ x,
    const _Float16* __restrict__ Bh,
    const _Float16* __restrict__ Bl,
    const float* __restrict__ noise_w,
    const float* __restrict__ noise,
    float* __restrict__ out)
{
    __shared__ _Float16 xh[2][MT * XSTR];    // 4.6 KB
    __shared__ _Float16 xl[2][MT * XSTR];    // 4.6 KB
    __shared__ float    cbuf[2][MT * CSTR];  // 8.4 KB

    const int tid  = threadIdx.x;
    const int lane = tid & 63;
    const int w    = __builtin_amdgcn_readfirstlane(tid >> 6);
    const int s    = w >> 2;                 // K-half (0/1)
    const int nt   = w & 3;                  // n-tile (16 experts)
    const int tokBase = blockIdx.x * MT;

    // staging: 256 threads per K-half; thread loads 4 fp32 (one float4)
    const int hid  = tid & 255;
    const int srow = hid >> 4;               // token 0..15
    const int scol = (hid & 15) * 4;         // k-local 0..60
    const float* xsrc = x + (size_t)(tokBase + srow) * DDIM + s * KHALF + scol;

    const int q = lane >> 4;                 // quad 0..3
    const int m = lane & 15;                 // token-in-tile / expert-in-tile
    const int abase = m * XSTR + q * 8;      // A-frag halves offset in xh[s]

    f32x4 acc_hh = {0.f, 0.f, 0.f, 0.f};
    f32x4 acc_lo = {0.f, 0.f, 0.f, 0.f};

    float4 stage = *(const float4*)xsrc;

    for (int c = 0; c < NCH; ++c) {
        __syncthreads();                     // waves done reading chunk c-1
        {   // split + store staged x
            f16x4 h4, l4;
            const float vv[4] = {stage.x, stage.y, stage.z, stage.w};
#pragma unroll
            for (int j = 0; j < 4; ++j) {
                const _Float16 h = (_Float16)vv[j];
                h4[j] = h;
                l4[j] = (_Float16)((vv[j] - (float)h) * 4096.f);
            }
            *(f16x4*)&xh[s][srow * XSTR + scol] = h4;
            *(f16x4*)&xl[s][srow * XSTR + scol] = l4;
        }
        if (c + 1 < NCH)
            stage = *(const float4*)(xsrc + (size_t)(c + 1) * BK);
        __syncthreads();                     // xh/xl ready

        const size_t ks0 = (size_t)s * 32 + 2 * c;   // global k-step
        const f16x8 bh0 = *(const f16x8*)(Bh + (((ks0    ) * 4 + nt) * 64 + lane) * 8);
        const f16x8 bh1 = *(const f16x8*)(Bh + (((ks0 + 1) * 4 + nt) * 64 + lane) * 8);
        const f16x8 bl0 = *(const f16x8*)(Bl + (((ks0    ) * 4 + nt) * 64 + lane) * 8);
        const f16x8 bl1 = *(const f16x8*)(Bl + (((ks0 + 1) * 4 + nt) * 64 + lane) * 8);

        const f16x8 ah0 = *(const f16x8*)&xh[s][abase];        // k-local 0..31
        const f16x8 ah1 = *(const f16x8*)&xh[s][abase + 32];   // k-local 32..63
        const f16x8 al0 = *(const f16x8*)&xl[s][abase];
        const f16x8 al1 = *(const f16x8*)&xl[s][abase + 32];

        acc_hh = __builtin_amdgcn_mfma_f32_16x16x32_f16(ah0, bh0, acc_hh, 0, 0, 0);
        acc_hh = __builtin_amdgcn_mfma_f32_16x16x32_f16(ah1, bh1, acc_hh, 0, 0, 0);
        acc_lo = __builtin_amdgcn_mfma_f32_16x16x32_f16(ah0, bl0, acc_lo, 0, 0, 0);
        acc_lo = __builtin_amdgcn_mfma_f32_16x16x32_f16(al0, bh0, acc_lo, 0, 0, 0);
        acc_lo = __builtin_amdgcn_mfma_f32_16x16x32_f16(ah1, bl1, acc_lo, 0, 0, 0);
        acc_lo = __builtin_amdgcn_mfma_f32_16x16x32_f16(al1, bh1, acc_lo, 0, 0, 0);
    }

    // combine passes, write C-buffer. C/D layout: col(e)=lane&15, row(t)=q*4+r.
    {
        const int e = nt * 16 + m;
#pragma unroll
        for (int r = 0; r < 4; ++r) {
            const int t = q * 4 + r;
            cbuf[s][t * CSTR + e] = acc_hh[r] + acc_lo[r] * (1.f / 4096.f);
        }
    }
    __syncthreads();

    // Epilogue: wave w owns tokens w*2, w*2+1; lane = expert.
    const float nwv = noise_w[lane];
#pragma unroll
    for (int i = 0; i < 2; ++i) {
        const int t   = w * 2 + i;
        const int tok = tokBase + t;
        const int e   = lane;

        float v = cbuf[0][t * CSTR + e] + cbuf[1][t * CSTR + e]
                + noise[(size_t)tok * NEXP + e] * nwv;

        // top-1: butterfly max, lax.top_k tie-break (lower index wins)
        float m1 = v; int i1 = e;
#pragma unroll
        for (int sh = 32; sh > 0; sh >>= 1) {
            float ov = __shfl_xor(m1, sh, 64);
            int   oi = __shfl_xor(i1, sh, 64);
            if (ov > m1 || (ov == m1 && oi < i1)) { m1 = ov; i1 = oi; }
        }
        float vm = (e == i1) ? -INFINITY : v;
        float m2 = vm; int i2 = e;
#pragma unroll
        for (int sh = 32; sh > 0; sh >>= 1) {
            float ov = __shfl_xor(m2, sh, 64);
            int   oi = __shfl_xor(i2, sh, 64);
            if (ov > m2 || (ov == m2 && oi < i2)) { m2 = ov; i2 = oi; }
        }

        const float e2  = expf(m2 - m1);
        const float inv = 1.f / (1.f + e2);
        const float p1  = inv;
        const float p2  = e2 * inv;

        float gval = 0.f;
        if (e == i1) gval = p1;
        else if (e == i2) gval = p2;
        out[(size_t)tok * NEXP + e] = gval;   // writes all 64 (d_out poisoned)

        if (lane == 0) {
            out[IDX_OFF  + tok * 2 + 0] = (float)i1;
            out[IDX_OFF  + tok * 2 + 1] = (float)i2;
            out[VALS_OFF + tok * 2 + 0] = m1;
            out[VALS_OFF + tok * 2 + 1] = m2;
        }
    }
}

extern "C" void kernel_launch(void* const* d_in, const int* in_sizes, int n_in,
                              void* d_out, int out_size, void* d_ws, size_t ws_size,
                              hipStream_t stream) {
    const float* x      = (const float*)d_in[0];
    const float* W      = (const float*)d_in[1];
    const float* nw     = (const float*)d_in[2];
    const float* noise  = (const float*)d_in[3];
    // d_in[4] is k==2, hardcoded
    float* out = (float*)d_out;

    _Float16* Bh = (_Float16*)d_ws;                 // 256 KB
    _Float16* Bl = Bh + BFRAG_HALVES;               // 256 KB

    hipLaunchKernelGGL(pack_b_kernel, dim3(64), dim3(256), 0, stream, W, Bh, Bl);

    hipLaunchKernelGGL(gate_kernel, dim3(NTOK / MT), dim3(512), 0, stream,
                       x, Bh, Bl, nw, noise, out);
}

// Round 8
// 116.756 us; speedup vs baseline: 2.0265x; 1.0005x over previous
//
#include <hip/hip_runtime.h>
#include <math.h>

// Problem: B=4,S=2048,D=2048,E=64,K=2 -> tokens 8192, K-dim 2048, experts 64
#define NTOK 8192
#define DDIM 2048
#define NEXP 64
#define MT   16          // tokens per block
#define BK   64          // k per chunk
#define KHALF 1024       // per-block K-split half
#define NCH  (KHALF / BK) // 16 chunks
#define XSTR 72          // x LDS row stride (halves)
#define CSTR 66          // C-buffer row stride (floats)

typedef _Float16 f16x8 __attribute__((ext_vector_type(8)));
typedef _Float16 f16x4 __attribute__((ext_vector_type(4)));
typedef float    f32x4 __attribute__((ext_vector_type(4)));

#define GATED_SZ (NTOK * NEXP)
#define IDX_OFF  GATED_SZ
#define VALS_OFF (GATED_SZ + NTOK * 2)

#define NKSTEP (DDIM / 32)            // 64 MFMA k-steps
#define NTILE  (NEXP / 16)            // 4 n-tiles
#define BFRAG_HALVES ((size_t)NKSTEP * NTILE * 64 * 8)   // 131072 halves

// ---------------------------------------------------------------------------
// Pack W [E=64][D=2048] into MFMA B-fragments (fp16 hi + 4096-scaled lo).
// Frag (ks, nt): lane holds B[k=ks*32+(lane>>4)*8+j][n=nt*16+(lane&15)].
// Layout: Bh[((ks*4+nt)*64+lane)*8 + j]. (Verified absmax=0 in round 6.)
// ---------------------------------------------------------------------------
__global__ void pack_b_kernel(const float* __restrict__ W,
                              _Float16* __restrict__ Bh,
                              _Float16* __restrict__ Bl)
{
    const int tid  = blockIdx.x * blockDim.x + threadIdx.x;  // 0..16383
    const int lane = tid & 63;
    const int fid  = tid >> 6;
    const int ks   = fid >> 2;
    const int nt   = fid & 3;
    const int e    = nt * 16 + (lane & 15);
    const int k    = ks * 32 + (lane >> 4) * 8;
    const float* src = W + (size_t)e * DDIM + k;

    f16x8 hi, lo;
#pragma unroll
    for (int j = 0; j < 8; ++j) {
        const float v = src[j];
        const _Float16 h = (_Float16)v;
        hi[j] = h;
        lo[j] = (_Float16)((v - (float)h) * 4096.f);
    }
    *(f16x8*)(Bh + (size_t)tid * 8) = hi;
    *(f16x8*)(Bl + (size_t)tid * 8) = lo;
}

#define BFRAG(base, ks) (*(const f16x8*)((base) + ((((size_t)(ks)) * 4 + nt) * 64 + lane) * 8))

// ---------------------------------------------------------------------------
// Fused gate kernel. 512 blocks x 512 thr; block = 16 tokens, full E=64.
// 8 waves = s (K-half) x nt (16-expert tile). Pipelined K-loop:
//   x prefetch depth 2 (regs), B prefetch depth 1 (regs), LDS buffers
//   indexed [s][parity] (round-7 bug: parity-only indexing let the two
//   K-half staging groups race on the same LDS lines), ONE barrier/chunk.
// Ordering: B-frag loads issued after the x prefetch -> MFMA vmcnt waits
// retire only B frags, never drain the deep x prefetch (round-6 stall).
// logits = acc_hh + 2^-12 * acc_lo  (x_lo,w_lo pre-scaled by 4096).
// ---------------------------------------------------------------------------
__global__ __launch_bounds__(512, 4) void gate_kernel(
    const float* __restrict__ x,
    const _Float16* __restrict__ Bh,
    const _Float16* __restrict__ Bl,
    const float* __restrict__ noise_w,
    const float* __restrict__ noise,
    float* __restrict__ out)
{
    __shared__ _Float16 xh[2][2][MT * XSTR];  // [K-half][parity] 9.2 KB
    __shared__ _Float16 xl[2][2][MT * XSTR];  // 9.2 KB
    __shared__ float    cbuf[2][MT * CSTR];   // 8.4 KB

    const int tid  = threadIdx.x;
    const int lane = tid & 63;
    const int w    = __builtin_amdgcn_readfirstlane(tid >> 6);
    const int s    = w >> 2;                 // K-half (0/1)
    const int nt   = w & 3;                  // n-tile (16 experts)
    const int tokBase = blockIdx.x * MT;

    // staging: 256 threads per K-half; thread loads one float4 of x per chunk
    const int hid  = tid & 255;
    const int srow = hid >> 4;               // token 0..15
    const int scol = (hid & 15) * 4;         // k-local 0..60
    const float* xsrc = x + (size_t)(tokBase + srow) * DDIM + s * KHALF + scol;

    const int q = lane >> 4;                 // quad 0..3
    const int m = lane & 15;
    const int abase = m * XSTR + q * 8;      // A-frag halves offset

    f32x4 acc_hh = {0.f, 0.f, 0.f, 0.f};
    f32x4 acc_lo = {0.f, 0.f, 0.f, 0.f};

    // ---- pipeline prologue: x chunks 0,1 ; B chunk 0 ----
    float4 xsreg[2];
    xsreg[0] = *(const float4*)xsrc;
    xsreg[1] = *(const float4*)(xsrc + BK);

    const int ksb = s * 32;                  // this K-half's first k-step
    f16x8 bh0c = BFRAG(Bh, ksb + 0);
    f16x8 bh1c = BFRAG(Bh, ksb + 1);
    f16x8 bl0c = BFRAG(Bl, ksb + 0);
    f16x8 bl1c = BFRAG(Bl, ksb + 1);

#pragma unroll
    for (int c = 0; c < NCH; ++c) {
        const int p = c & 1;

        // split + store staged x (loaded 2 chunks ago -> vmcnt wait is cheap)
        {
            const float4 sv = xsreg[p];
            const float vv[4] = {sv.x, sv.y, sv.z, sv.w};
            f16x4 h4, l4;
#pragma unroll
            for (int j = 0; j < 4; ++j) {
                const _Float16 h = (_Float16)vv[j];
                h4[j] = h;
                l4[j] = (_Float16)((vv[j] - (float)h) * 4096.f);
            }
            *(f16x4*)&xh[s][p][srow * XSTR + scol] = h4;
            *(f16x4*)&xl[s][p][srow * XSTR + scol] = l4;
        }

        // prefetch x chunk c+2 (depth-2 covers ~900cyc HBM latency)
        if (c + 2 < NCH)
            xsreg[p] = *(const float4*)(xsrc + (size_t)(c + 2) * BK);

        // prefetch B chunk c+1 (AFTER the x prefetch in issue order)
        const int cn = (c + 1 < NCH) ? (c + 1) : 0;   // dummy on last iter
        f16x8 bh0n = BFRAG(Bh, ksb + 2 * cn);
        f16x8 bh1n = BFRAG(Bh, ksb + 2 * cn + 1);
        f16x8 bl0n = BFRAG(Bl, ksb + 2 * cn);
        f16x8 bl1n = BFRAG(Bl, ksb + 2 * cn + 1);

        __syncthreads();                     // xh/xl[s][p] ready for all waves
        // write(c+2) to this parity happens only after barrier(c+1), by which
        // time every wave's reads(c) are drained -> single barrier is safe.

        const f16x8 ah0 = *(const f16x8*)&xh[s][p][abase];        // k 0..31
        const f16x8 ah1 = *(const f16x8*)&xh[s][p][abase + 32];   // k 32..63
        const f16x8 al0 = *(const f16x8*)&xl[s][p][abase];
        const f16x8 al1 = *(const f16x8*)&xl[s][p][abase + 32];

        acc_hh = __builtin_amdgcn_mfma_f32_16x16x32_f16(ah0, bh0c, acc_hh, 0, 0, 0);
        acc_hh = __builtin_amdgcn_mfma_f32_16x16x32_f16(ah1, bh1c, acc_hh, 0, 0, 0);
        acc_lo = __builtin_amdgcn_mfma_f32_16x16x32_f16(ah0, bl0c, acc_lo, 0, 0, 0);
        acc_lo = __builtin_amdgcn_mfma_f32_16x16x32_f16(al0, bh0c, acc_lo, 0, 0, 0);
        acc_lo = __builtin_amdgcn_mfma_f32_16x16x32_f16(ah1, bl1c, acc_lo, 0, 0, 0);
        acc_lo = __builtin_amdgcn_mfma_f32_16x16x32_f16(al1, bh1c, acc_lo, 0, 0, 0);

        bh0c = bh0n; bh1c = bh1n; bl0c = bl0n; bl1c = bl1n;
    }

    // combine passes -> C-buffer. C/D layout: col(e)=lane&15, row(t)=q*4+r.
    {
        const int e = nt * 16 + m;
#pragma unroll
        for (int r = 0; r < 4; ++r) {
            const int t = q * 4 + r;
            cbuf[s][t * CSTR + e] = acc_hh[r] + acc_lo[r] * (1.f / 4096.f);
        }
    }
    __syncthreads();

    // Epilogue: wave w owns tokens w*2, w*2+1; lane = expert.
    const float nwv = noise_w[lane];
#pragma unroll
    for (int i = 0; i < 2; ++i) {
        const int t   = w * 2 + i;
        const int tok = tokBase + t;
        const int e   = lane;

        float v = cbuf[0][t * CSTR + e] + cbuf[1][t * CSTR + e]
                + noise[(size_t)tok * NEXP + e] * nwv;

        // top-1: butterfly max, lax.top_k tie-break (lower index wins)
        float m1 = v; int i1 = e;
#pragma unroll
        for (int sh = 32; sh > 0; sh >>= 1) {
            float ov = __shfl_xor(m1, sh, 64);
            int   oi = __shfl_xor(i1, sh, 64);
            if (ov > m1 || (ov == m1 && oi < i1)) { m1 = ov; i1 = oi; }
        }
        float vm = (e == i1) ? -INFINITY : v;
        float m2 = vm; int i2 = e;
#pragma unroll
        for (int sh = 32; sh > 0; sh >>= 1) {
            float ov = __shfl_xor(m2, sh, 64);
            int   oi = __shfl_xor(i2, sh, 64);
            if (ov > m2 || (ov == m2 && oi < i2)) { m2 = ov; i2 = oi; }
        }

        const float e2  = expf(m2 - m1);
        const float inv = 1.f / (1.f + e2);
        const float p1  = inv;
        const float p2  = e2 * inv;

        float gval = 0.f;
        if (e == i1) gval = p1;
        else if (e == i2) gval = p2;
        out[(size_t)tok * NEXP + e] = gval;

        if (lane == 0) {
            out[IDX_OFF  + tok * 2 + 0] = (float)i1;
            out[IDX_OFF  + tok * 2 + 1] = (float)i2;
            out[VALS_OFF + tok * 2 + 0] = m1;
            out[VALS_OFF + tok * 2 + 1] = m2;
        }
    }
}

extern "C" void kernel_launch(void* const* d_in, const int* in_sizes, int n_in,
                              void* d_out, int out_size, void* d_ws, size_t ws_size,
                              hipStream_t stream) {
    const float* x      = (const float*)d_in[0];
    const float* W      = (const float*)d_in[1];
    const float* nw     = (const float*)d_in[2];
    const float* noise  = (const float*)d_in[3];
    // d_in[4] is k==2, hardcoded
    float* out = (float*)d_out;

    _Float16* Bh = (_Float16*)d_ws;                 // 256 KB
    _Float16* Bl = Bh + BFRAG_HALVES;               // 256 KB

    hipLaunchKernelGGL(pack_b_kernel, dim3(64), dim3(256), 0, stream, W, Bh, Bl);

    hipLaunchKernelGGL(gate_kernel, dim3(NTOK / MT), dim3(512), 0, stream,
                       x, Bh, Bl, nw, noise, out);
}

// Round 9
// 112.512 us; speedup vs baseline: 2.1030x; 1.0377x over previous
//
#include <hip/hip_runtime.h>
#include <math.h>

// Problem: B=4,S=2048,D=2048,E=64,K=2 -> tokens 8192, K-dim 2048, experts 64
#define NTOK 8192
#define DDIM 2048
#define NEXP 64
#define MT   16            // tokens per block
#define BK   256           // k per chunk (4x round 8: amortize barrier/latency)
#define NCH  (DDIM / BK)   // 8 chunks
#define XSTR 264           // x LDS row stride in halves (256 + 8 pad)
#define CSTR 66            // C-buffer row stride (floats)

typedef _Float16 f16x8 __attribute__((ext_vector_type(8)));
typedef float    f32x4 __attribute__((ext_vector_type(4)));

#define GATED_SZ (NTOK * NEXP)
#define IDX_OFF  GATED_SZ
#define VALS_OFF (GATED_SZ + NTOK * 2)

#define NKSTEP (DDIM / 32)            // 64 MFMA k-steps
#define NTILE  (NEXP / 16)            // 4 n-tiles
#define BFRAG_HALVES ((size_t)NKSTEP * NTILE * 64 * 8)   // 131072 halves

// ---------------------------------------------------------------------------
// Pack W [E=64][D=2048] into MFMA B-fragments (fp16 hi + 4096-scaled lo).
// Frag (ks, nt): lane holds B[k=ks*32+(lane>>4)*8+j][n=nt*16+(lane&15)].
// Layout: Bh[((ks*4+nt)*64+lane)*8 + j]. (Verified absmax=0, rounds 6/8.)
// ---------------------------------------------------------------------------
__global__ void pack_b_kernel(const float* __restrict__ W,
                              _Float16* __restrict__ Bh,
                              _Float16* __restrict__ Bl)
{
    const int tid  = blockIdx.x * blockDim.x + threadIdx.x;  // 0..16383
    const int lane = tid & 63;
    const int fid  = tid >> 6;
    const int ks   = fid >> 2;
    const int nt   = fid & 3;
    const int e    = nt * 16 + (lane & 15);
    const int k    = ks * 32 + (lane >> 4) * 8;
    const float* src = W + (size_t)e * DDIM + k;

    f16x8 hi, lo;
#pragma unroll
    for (int j = 0; j < 8; ++j) {
        const float v = src[j];
        const _Float16 h = (_Float16)v;
        hi[j] = h;
        lo[j] = (_Float16)((v - (float)h) * 4096.f);
    }
    *(f16x8*)(Bh + (size_t)tid * 8) = hi;
    *(f16x8*)(Bl + (size_t)tid * 8) = lo;
}

#define BFRAG(base, ks) (*(const f16x8*)((base) + ((((size_t)(ks)) * 4 + nt) * 64 + lane) * 8))

// ---------------------------------------------------------------------------
// Fused gate kernel. 512 blocks x 512 thr; block = 16 tokens, full E=64.
// 8 waves = h (k-half of chunk) x nt (16-expert tile). 8 chunks of 256 k:
// per chunk: cooperative x stage (fp32 -> hi/lo fp16) into parity-buffered
// LDS, ONE barrier, then each wave does 4 k-steps (2 B loads + 2 A ds_reads
// + 3 MFMAs per 32-k step). Big chunks amortize the barrier 4x vs round 8.
// logits = acc_hh + 2^-12 * acc_lo (x_lo,w_lo pre-scaled by 4096).
// Epilogue: sum the 2 k-half partials via LDS, noise, top-2, softmax.
// ---------------------------------------------------------------------------
__global__ __launch_bounds__(512, 4) void gate_kernel(
    const float* __restrict__ x,
    const _Float16* __restrict__ Bh,
    const _Float16* __restrict__ Bl,
    const float* __restrict__ noise_w,
    const float* __restrict__ noise,
    float* __restrict__ out)
{
    __shared__ _Float16 xh[2][MT * XSTR];    // [parity] 16.5 KB
    __shared__ _Float16 xl[2][MT * XSTR];    // 16.5 KB
    __shared__ float    cbuf[2][MT * CSTR];  // 8.4 KB

    const int tid  = threadIdx.x;
    const int lane = tid & 63;
    const int w    = __builtin_amdgcn_readfirstlane(tid >> 6);
    const int h    = w >> 2;                 // k-half of chunk (0/1)
    const int nt   = w & 3;                  // n-tile (16 experts)
    const int tokBase = blockIdx.x * MT;

    // staging: thread covers token srow, 8 consecutive k at scol*8
    const int srow = tid >> 5;               // 0..15
    const int scol = tid & 31;               // 0..31 (8-float groups)
    const float* xsrc = x + (size_t)(tokBase + srow) * DDIM + scol * 8;

    const int q = lane >> 4;                 // quad 0..3
    const int m = lane & 15;
    const int abase = m * XSTR + h * (BK / 2) + q * 8;  // A-frag base (halves)

    f32x4 acc_hh = {0.f, 0.f, 0.f, 0.f};
    f32x4 acc_lo = {0.f, 0.f, 0.f, 0.f};

    // prologue: load chunk 0 into stage regs
    float4 st0 = *(const float4*)(xsrc);
    float4 st1 = *(const float4*)(xsrc + 4);

    for (int c = 0; c < NCH; ++c) {
        const int p = c & 1;

        // convert + store staged x (hi/lo), one f16x8 each
        {
            f16x8 h8, l8;
            const float vv[8] = {st0.x, st0.y, st0.z, st0.w,
                                 st1.x, st1.y, st1.z, st1.w};
#pragma unroll
            for (int j = 0; j < 8; ++j) {
                const _Float16 hh = (_Float16)vv[j];
                h8[j] = hh;
                l8[j] = (_Float16)((vv[j] - (float)hh) * 4096.f);
            }
            *(f16x8*)&xh[p][srow * XSTR + scol * 8] = h8;
            *(f16x8*)&xl[p][srow * XSTR + scol * 8] = l8;
        }

        // prefetch chunk c+1 (depth-1; chunk time >> HBM latency now)
        if (c + 1 < NCH) {
            st0 = *(const float4*)(xsrc + (size_t)(c + 1) * BK);
            st1 = *(const float4*)(xsrc + (size_t)(c + 1) * BK + 4);
        }

        __syncthreads();
        // single barrier/chunk is safe: this wave writes parity p^1 (iter
        // c+1) only after this barrier, by which time every wave's reads of
        // parity p^1 (iter c-1) have retired.

        const int ksb = c * 8 + h * 4;       // wave's first k-step this chunk
#pragma unroll
        for (int stp = 0; stp < 4; ++stp) {
            const f16x8 bh = BFRAG(Bh, ksb + stp);
            const f16x8 bl = BFRAG(Bl, ksb + stp);
            const f16x8 ah = *(const f16x8*)&xh[p][abase + stp * 32];
            const f16x8 al = *(const f16x8*)&xl[p][abase + stp * 32];
            acc_hh = __builtin_amdgcn_mfma_f32_16x16x32_f16(ah, bh, acc_hh, 0, 0, 0);
            acc_lo = __builtin_amdgcn_mfma_f32_16x16x32_f16(ah, bl, acc_lo, 0, 0, 0);
            acc_lo = __builtin_amdgcn_mfma_f32_16x16x32_f16(al, bh, acc_lo, 0, 0, 0);
        }
    }

    // combine passes -> C-buffer. C/D layout: col(e)=lane&15, row(t)=q*4+r.
    {
        const int e = nt * 16 + m;
#pragma unroll
        for (int r = 0; r < 4; ++r) {
            const int t = q * 4 + r;
            cbuf[h][t * CSTR + e] = acc_hh[r] + acc_lo[r] * (1.f / 4096.f);
        }
    }
    __syncthreads();

    // Epilogue: wave w owns tokens w*2, w*2+1; lane = expert.
    const float nwv = noise_w[lane];
#pragma unroll
    for (int i = 0; i < 2; ++i) {
        const int t   = w * 2 + i;
        const int tok = tokBase + t;
        const int e   = lane;

        float v = cbuf[0][t * CSTR + e] + cbuf[1][t * CSTR + e]
                + noise[(size_t)tok * NEXP + e] * nwv;

        // top-1: butterfly max, lax.top_k tie-break (lower index wins)
        float m1 = v; int i1 = e;
#pragma unroll
        for (int sh = 32; sh > 0; sh >>= 1) {
            float ov = __shfl_xor(m1, sh, 64);
            int   oi = __shfl_xor(i1, sh, 64);
            if (ov > m1 || (ov == m1 && oi < i1)) { m1 = ov; i1 = oi; }
        }
        float vm = (e == i1) ? -INFINITY : v;
        float m2 = vm; int i2 = e;
#pragma unroll
        for (int sh = 32; sh > 0; sh >>= 1) {
            float ov = __shfl_xor(m2, sh, 64);
            int   oi = __shfl_xor(i2, sh, 64);
            if (ov > m2 || (ov == m2 && oi < i2)) { m2 = ov; i2 = oi; }
        }

        const float e2  = expf(m2 - m1);
        const float inv = 1.f / (1.f + e2);
        const float p1  = inv;
        const float p2  = e2 * inv;

        float gval = 0.f;
        if (e == i1) gval = p1;
        else if (e == i2) gval = p2;
        out[(size_t)tok * NEXP + e] = gval;

        if (lane == 0) {
            out[IDX_OFF  + tok * 2 + 0] = (float)i1;
            out[IDX_OFF  + tok * 2 + 1] = (float)i2;
            out[VALS_OFF + tok * 2 + 0] = m1;
            out[VALS_OFF + tok * 2 + 1] = m2;
        }
    }
}

extern "C" void kernel_launch(void* const* d_in, const int* in_sizes, int n_in,
                              void* d_out, int out_size, void* d_ws, size_t ws_size,
                              hipStream_t stream) {
    const float* x      = (const float*)d_in[0];
    const float* W      = (const float*)d_in[1];
    const float* nw     = (const float*)d_in[2];
    const float* noise  = (const float*)d_in[3];
    // d_in[4] is k==2, hardcoded
    float* out = (float*)d_out;

    _Float16* Bh = (_Float16*)d_ws;                 // 256 KB
    _Float16* Bl = Bh + BFRAG_HALVES;               // 256 KB

    hipLaunchKernelGGL(pack_b_kernel, dim3(64), dim3(256), 0, stream, W, Bh, Bl);

    hipLaunchKernelGGL(gate_kernel, dim3(NTOK / MT), dim3(512), 0, stream,
                       x, Bh, Bl, nw, noise, out);
}